// Round 1
// baseline (381.082 us; speedup 1.0000x reference)
//
#include <hip/hip_runtime.h>

// MS-SSIM loss, 5 levels, fused per-level kernel.
// Tile: 64 (cols) x 32 (rows) outputs per 256-thread block.
// Phase H: horizontal 11-tap Gaussian of {x, y, x^2, y^2, x*y} from global
//          (L1-cached halo reuse), written TRANSPOSED to LDS (pitch 44 ->
//          phase-V reads are contiguous 16B ds_read_b128, ~2-way banks = free).
// Phase V: vertical 11-tap conv in registers + fused SSIM + block reduction
//          + one atomicAdd per block. Avg-pool for the next level fused in.

#define TW 64
#define TH 32
#define HHALO 42            // TH + 10
#define HPITCH 44           // HHALO padded (keeps 16B alignment, good banks)
#define PLANE (TW * HPITCH) // 2816 floats per field plane
#define NIMG 48             // 16 * 3

__global__ __launch_bounds__(256, 2) void ssim_level_kernel(
    const float* __restrict__ x, const float* __restrict__ y,
    float* __restrict__ dsx, float* __restrict__ dsy,
    float* __restrict__ sum_out, int H, int W, int do_ds)
{
    // Gaussian(11, sigma=1.5), normalized (matches jnp fp32 to ~1e-7)
    const float G[11] = {
        0.00102839f, 0.00759877f, 0.03600077f, 0.10936069f, 0.21300539f,
        0.26601173f, 0.21300539f, 0.10936069f, 0.03600077f, 0.00759877f,
        0.00102839f};
    const float C1 = 4.0e-4f;   // (0.01*2)^2
    const float C2 = 3.6e-3f;   // (0.03*2)^2

    __shared__ __align__(16) float hfT[5 * PLANE];
    __shared__ float wred[4];

    const int t   = threadIdx.x;
    const int img = blockIdx.z;
    const int C0  = blockIdx.x * TW;
    const int R0  = blockIdx.y * TH;
    const long base = (long)img * H * W;

    // ---- fused avg-pool 2x2 for next level (independent of phase H) ----
    if (do_ds) {
        const int dsW = W >> 1, dsH = H >> 1;
        const long dbase = (long)img * dsH * dsW;
        for (int i = t; i < (TW / 2) * (TH / 2); i += 256) {
            const int dr = i >> 5;       // / (TW/2)
            const int dc = i & 31;       // % (TW/2)
            const int gr2 = (R0 >> 1) + dr;
            const int gc2 = (C0 >> 1) + dc;
            if (gr2 < dsH && gc2 < dsW) {
                const long src = base + (long)(2 * gr2) * W + 2 * gc2;
                dsx[dbase + (long)gr2 * dsW + gc2] =
                    0.25f * (x[src] + x[src + 1] + x[src + W] + x[src + W + 1]);
                dsy[dbase + (long)gr2 * dsW + gc2] =
                    0.25f * (y[src] + y[src + 1] + y[src + W] + y[src + W + 1]);
            }
        }
    }

    // ---- Phase H: 42 halo rows x 8 col-octets = 336 strips ----
    for (int s = t; s < HHALO * (TW / 8); s += 256) {
        const int r  = s >> 3;
        const int c0 = (s & 7) << 3;
        const int gr = R0 + r - 5;
        const bool rok = ((unsigned)gr < (unsigned)H);
        const float* xrow = x + base + (long)gr * W;
        const float* yrow = y + base + (long)gr * W;
        float xv[18], yv[18];
#pragma unroll
        for (int k = 0; k < 18; ++k) {
            const int gc = C0 + c0 + k - 5;
            const bool ok = rok && ((unsigned)gc < (unsigned)W);
            xv[k] = ok ? xrow[gc] : 0.0f;
            yv[k] = ok ? yrow[gc] : 0.0f;
        }
#pragma unroll
        for (int j = 0; j < 8; ++j) {
            float hx = 0.f, hy = 0.f, hxx = 0.f, hyy = 0.f, hxy = 0.f;
#pragma unroll
            for (int k = 0; k < 11; ++k) {
                const float xk = xv[j + k], yk = yv[j + k];
                const float gx = G[k] * xk, gy = G[k] * yk;
                hx += gx;
                hy += gy;
                hxx = fmaf(gx, xk, hxx);
                hyy = fmaf(gy, yk, hyy);
                hxy = fmaf(gx, yk, hxy);
            }
            const int cc = c0 + j;
            float* hp = &hfT[cc * HPITCH + r];
            hp[0 * PLANE] = hx;
            hp[1 * PLANE] = hy;
            hp[2 * PLANE] = hxx;
            hp[3 * PLANE] = hyy;
            hp[4 * PLANE] = hxy;
        }
    }
    __syncthreads();

    // ---- Phase V: thread = (col, 8-row strip); 64 x 4 = 256 strips ----
    const int c  = t & 63;
    const int r0 = (t >> 6) << 3;
    float acc[5][8];
#pragma unroll
    for (int f = 0; f < 5; ++f) {
        const float* hp = &hfT[f * PLANE + c * HPITCH + r0];
        float hv[18];
        const float4 a0 = *reinterpret_cast<const float4*>(hp);
        const float4 a1 = *reinterpret_cast<const float4*>(hp + 4);
        const float4 a2 = *reinterpret_cast<const float4*>(hp + 8);
        const float4 a3 = *reinterpret_cast<const float4*>(hp + 12);
        const float2 a4 = *reinterpret_cast<const float2*>(hp + 16);
        hv[0] = a0.x;  hv[1] = a0.y;  hv[2] = a0.z;  hv[3] = a0.w;
        hv[4] = a1.x;  hv[5] = a1.y;  hv[6] = a1.z;  hv[7] = a1.w;
        hv[8] = a2.x;  hv[9] = a2.y;  hv[10] = a2.z; hv[11] = a2.w;
        hv[12] = a3.x; hv[13] = a3.y; hv[14] = a3.z; hv[15] = a3.w;
        hv[16] = a4.x; hv[17] = a4.y;
#pragma unroll
        for (int i = 0; i < 8; ++i) {
            float a = 0.f;
#pragma unroll
            for (int k = 0; k < 11; ++k) a = fmaf(G[k], hv[i + k], a);
            acc[f][i] = a;
        }
    }

    float local = 0.f;
#pragma unroll
    for (int i = 0; i < 8; ++i) {
        const int gr = R0 + r0 + i;
        const int gc = C0 + c;
        if (gr < H && gc < W) {
            const float mu1 = acc[0][i], mu2 = acc[1][i];
            const float mu1s = mu1 * mu1, mu2s = mu2 * mu2, m12 = mu1 * mu2;
            const float s1  = acc[2][i] - mu1s;
            const float s2  = acc[3][i] - mu2s;
            const float s12 = acc[4][i] - m12;
            const float num = (2.f * m12 + C1) * (2.f * s12 + C2);
            const float den = (mu1s + mu2s + C1) * (s1 + s2 + C2);
            local += num / (den + 1e-8f);
        }
    }

    // ---- reduction: wave shuffle -> LDS -> one atomic per block ----
#pragma unroll
    for (int off = 32; off > 0; off >>= 1) local += __shfl_down(local, off, 64);
    if ((t & 63) == 0) wred[t >> 6] = local;
    __syncthreads();
    if (t == 0) atomicAdd(sum_out, wred[0] + wred[1] + wred[2] + wred[3]);
}

__global__ void finalize_kernel(const float* __restrict__ sums,
                                float* __restrict__ out)
{
    if (threadIdx.x == 0 && blockIdx.x == 0) {
        const float w[5] = {0.0448f, 0.2856f, 0.3001f, 0.2363f, 0.1333f};
        const float wsum = w[0] + w[1] + w[2] + w[3] + w[4];
        float acc = 0.f;
#pragma unroll
        for (int i = 0; i < 5; ++i) {
            const int d = 512 >> i;
            const float cnt = (float)NIMG * (float)d * (float)d;
            acc += (w[i] / wsum) * (sums[i] / cnt);
        }
        out[0] = 1.0f - acc;
    }
}

extern "C" void kernel_launch(void* const* d_in, const int* in_sizes, int n_in,
                              void* d_out, int out_size, void* d_ws, size_t ws_size,
                              hipStream_t stream)
{
    const float* pred = (const float*)d_in[0];
    const float* targ = (const float*)d_in[1];
    float* out = (float*)d_out;
    float* ws  = (float*)d_ws;

    // workspace layout (floats)
    float* sums = ws;                       // 8 floats (5 used)
    const long n1 = (long)NIMG * 256 * 256; // 3,145,728
    const long n2 = (long)NIMG * 128 * 128; //   786,432
    const long n3 = (long)NIMG * 64 * 64;   //   196,608
    const long n4 = (long)NIMG * 32 * 32;   //    49,152
    float* x1 = ws + 64;
    float* y1 = x1 + n1;
    float* x2 = y1 + n1;
    float* y2 = x2 + n2;
    float* x3 = y2 + n2;
    float* y3 = x3 + n3;
    float* x4 = y3 + n3;
    float* y4 = x4 + n4;

    hipMemsetAsync(sums, 0, 8 * sizeof(float), stream);

    // level 0: 512x512
    {
        dim3 grid(512 / TW, 512 / TH, NIMG);
        ssim_level_kernel<<<grid, 256, 0, stream>>>(pred, targ, x1, y1, sums + 0, 512, 512, 1);
    }
    // level 1: 256x256
    {
        dim3 grid(256 / TW, 256 / TH, NIMG);
        ssim_level_kernel<<<grid, 256, 0, stream>>>(x1, y1, x2, y2, sums + 1, 256, 256, 1);
    }
    // level 2: 128x128
    {
        dim3 grid(128 / TW, 128 / TH, NIMG);
        ssim_level_kernel<<<grid, 256, 0, stream>>>(x2, y2, x3, y3, sums + 2, 128, 128, 1);
    }
    // level 3: 64x64
    {
        dim3 grid(1, 64 / TH, NIMG);
        ssim_level_kernel<<<grid, 256, 0, stream>>>(x3, y3, x4, y4, sums + 3, 64, 64, 1);
    }
    // level 4: 32x32 (tile wider than image; masked; no downsample)
    {
        dim3 grid(1, 1, NIMG);
        ssim_level_kernel<<<grid, 256, 0, stream>>>(x4, y4, nullptr, nullptr, sums + 4, 32, 32, 0);
    }
    finalize_kernel<<<1, 64, 0, stream>>>(sums, out);
}